// Round 1
// baseline (450.284 us; speedup 1.0000x reference)
//
#include <hip/hip_runtime.h>
#include <hip/hip_bf16.h>

typedef short short8 __attribute__((ext_vector_type(8)));
typedef float f32x4 __attribute__((ext_vector_type(4)));

#define MFMA16(a, b, c) __builtin_amdgcn_mfma_f32_16x16x32_bf16(a, b, c, 0, 0, 0)

// fp32 -> bf16 round-to-nearest-even (bit trick; NaN not expected here)
__device__ __forceinline__ unsigned short f2b(float f) {
    union { float f; unsigned int u; } v;
    v.f = f;
    unsigned int u = v.u;
    unsigned int r = (u + 0x7fffu + ((u >> 16) & 1u)) >> 16;
    return (unsigned short)r;
}

// ---------------- convert fp32 -> bf16, 4 elems/thread ----------------
__global__ void cvt_kernel(const float* __restrict__ src,
                           unsigned short* __restrict__ dst, int n4) {
    int i = blockIdx.x * blockDim.x + threadIdx.x;
    if (i < n4) {
        float4 v = ((const float4*)src)[i];
        ushort4 o;
        o.x = f2b(v.x); o.y = f2b(v.y); o.z = f2b(v.z); o.w = f2b(v.w);
        ((ushort4*)dst)[i] = o;
    }
}

// ---------------- key mask: maskbuf[b*T+t] = 0 or -1e30 ----------------
__global__ void mask_kernel(const float* __restrict__ x, float* __restrict__ maskbuf) {
    int i = blockIdx.x * blockDim.x + threadIdx.x;
    if (i < 4096)
        maskbuf[i] = (x[(size_t)i * 1024] != 0.0f) ? 0.0f : -1e30f;
}

// ---------------- GEMM: out[m,n] = sum_k A[m,k]*Bw[n,k] + bias[n] ----------------
// A: [4096,1024] bf16 row-major, Bw: [1024,1024] bf16 row-major (torch Linear weight)
// mode 0: fp32 out row-major [M,N]
// mode 1: bf16 out (B,H,T,Dh)   (for Q, K)
// mode 2: bf16 out (B,H,Dh,T)   (for V, pre-transposed for the PV MFMA B-operand)
__global__ __launch_bounds__(256) void gemm_bt(
        const unsigned short* __restrict__ A, const unsigned short* __restrict__ Bw,
        const float* __restrict__ bias, void* __restrict__ out, int mode) {
    const int K = 1024, N = 1024;
    __shared__ unsigned short As[128 * 40];  // stride 40: 2-way (free) LDS banking
    __shared__ unsigned short Bs[128 * 40];

    int tid = threadIdx.x;
    int lane = tid & 63, wave = tid >> 6;
    int lane15 = lane & 15, quad = lane >> 4;
    int bm = blockIdx.y * 128, bn = blockIdx.x * 128;
    int wm = (wave >> 1) * 64, wn = (wave & 1) * 64;

    f32x4 acc[4][4];
#pragma unroll
    for (int i = 0; i < 4; i++)
#pragma unroll
        for (int j = 0; j < 4; j++) acc[i][j] = (f32x4){0.f, 0.f, 0.f, 0.f};

    int sr = tid >> 2;            // staging row 0..63
    int sc = (tid & 3) * 8;       // staging k-chunk

    for (int kb = 0; kb < K; kb += 32) {
        *(uint4*)&As[sr * 40 + sc]        = *(const uint4*)&A[(size_t)(bm + sr) * K + kb + sc];
        *(uint4*)&As[(sr + 64) * 40 + sc] = *(const uint4*)&A[(size_t)(bm + sr + 64) * K + kb + sc];
        *(uint4*)&Bs[sr * 40 + sc]        = *(const uint4*)&Bw[(size_t)(bn + sr) * K + kb + sc];
        *(uint4*)&Bs[(sr + 64) * 40 + sc] = *(const uint4*)&Bw[(size_t)(bn + sr + 64) * K + kb + sc];
        __syncthreads();

        short8 af[4], bf[4];
#pragma unroll
        for (int i = 0; i < 4; i++)
            af[i] = *(const short8*)&As[(wm + i * 16 + lane15) * 40 + quad * 8];
#pragma unroll
        for (int j = 0; j < 4; j++)
            bf[j] = *(const short8*)&Bs[(wn + j * 16 + lane15) * 40 + quad * 8];
#pragma unroll
        for (int i = 0; i < 4; i++)
#pragma unroll
            for (int j = 0; j < 4; j++)
                acc[i][j] = MFMA16(af[i], bf[j], acc[i][j]);
        __syncthreads();
    }

#pragma unroll
    for (int i = 0; i < 4; i++)
#pragma unroll
        for (int j = 0; j < 4; j++) {
            int n = bn + wn + j * 16 + lane15;
            float bv = bias[n];
#pragma unroll
            for (int r = 0; r < 4; r++) {
                int m = bm + wm + i * 16 + quad * 4 + r;
                float v = acc[i][j][r] + bv;
                if (mode == 0) {
                    ((float*)out)[(size_t)m * N + n] = v;
                } else {
                    int b = m >> 11, t = m & 2047, h = n >> 6, d = n & 63;
                    size_t off = (mode == 1)
                        ? ((size_t)((b * 16 + h) * 2048 + t) * 64 + d)
                        : ((size_t)((b * 16 + h) * 64 + d) * 2048 + t);
                    ((unsigned short*)out)[off] = f2b(v);
                }
            }
        }
}

// ---------------- flash attention ----------------
// grid (T/64, H, B), block 256. Wave w owns Q rows qt*64+w*16 .. +16.
// Q,K: (B,H,T,64) bf16; Vt: (B,H,64,T) bf16; attnout: (B,T,C) bf16
__global__ __launch_bounds__(256) void attn_kernel(
        const unsigned short* __restrict__ qbuf, const unsigned short* __restrict__ kbuf,
        const unsigned short* __restrict__ vtbuf, const float* __restrict__ maskbuf,
        unsigned short* __restrict__ attnout) {
    int b = blockIdx.z, h = blockIdx.y, qt = blockIdx.x;
    int lane = threadIdx.x & 63, wave = threadIdx.x >> 6;
    int lane15 = lane & 15, quad = lane >> 4;
    int q0 = qt * 64 + wave * 16;

    const unsigned short* Q  = qbuf  + (size_t)(b * 16 + h) * 2048 * 64;
    const unsigned short* Kp = kbuf  + (size_t)(b * 16 + h) * 2048 * 64;
    const unsigned short* Vt = vtbuf + (size_t)(b * 16 + h) * 64 * 2048;
    const float* mb = maskbuf + b * 2048;

    // Q A-fragments (row = lane15, k = quad*8..+8), K-dim 64 split in two
    short8 qf0 = *(const short8*)&Q[(size_t)(q0 + lane15) * 64 + quad * 8];
    short8 qf1 = *(const short8*)&Q[(size_t)(q0 + lane15) * 64 + 32 + quad * 8];

    float m_run[4], l_run[4];
    f32x4 o[4];
#pragma unroll
    for (int r = 0; r < 4; r++) { m_run[r] = -1e30f; l_run[r] = 0.f; }
#pragma unroll
    for (int c = 0; c < 4; c++) o[c] = (f32x4){0.f, 0.f, 0.f, 0.f};

    __shared__ unsigned short plds[4][16 * 40];   // per-wave P transpose tile
    unsigned short* myP = plds[wave];

    for (int kb = 0; kb < 2048; kb += 32) {
        f32x4 s0 = (f32x4){0.f, 0.f, 0.f, 0.f};
        f32x4 s1 = (f32x4){0.f, 0.f, 0.f, 0.f};
        // S = Q K^T : B-frag lane holds K[key=lane15][feat=quad*8+j]
        s0 = MFMA16(qf0, *(const short8*)&Kp[(size_t)(kb + lane15) * 64 + quad * 8], s0);
        s0 = MFMA16(qf1, *(const short8*)&Kp[(size_t)(kb + lane15) * 64 + 32 + quad * 8], s0);
        s1 = MFMA16(qf0, *(const short8*)&Kp[(size_t)(kb + 16 + lane15) * 64 + quad * 8], s1);
        s1 = MFMA16(qf1, *(const short8*)&Kp[(size_t)(kb + 16 + lane15) * 64 + 32 + quad * 8], s1);

        float mk0 = mb[kb + lane15];
        float mk1 = mb[kb + 16 + lane15];
        float alpha[4];
#pragma unroll
        for (int r = 0; r < 4; r++) {
            float v0 = s0[r] * 0.125f + mk0;    // scale then mask (additive -1e30)
            float v1 = s1[r] * 0.125f + mk1;
            float mx = fmaxf(v0, v1);
            mx = fmaxf(mx, __shfl_xor(mx, 1));
            mx = fmaxf(mx, __shfl_xor(mx, 2));
            mx = fmaxf(mx, __shfl_xor(mx, 4));
            mx = fmaxf(mx, __shfl_xor(mx, 8));
            float mnew = fmaxf(m_run[r], mx);
            v0 = __expf(v0 - mnew);
            v1 = __expf(v1 - mnew);
            float sum = v0 + v1;
            sum += __shfl_xor(sum, 1);
            sum += __shfl_xor(sum, 2);
            sum += __shfl_xor(sum, 4);
            sum += __shfl_xor(sum, 8);
            float a = __expf(m_run[r] - mnew);
            l_run[r] = l_run[r] * a + sum;
            m_run[r] = mnew;
            alpha[r] = a;
            // write P (C-layout: row=quad*4+r, col=lane15 / +16) to LDS
            myP[(quad * 4 + r) * 40 + lane15] = f2b(v0);
            myP[(quad * 4 + r) * 40 + 16 + lane15] = f2b(v1);
        }
#pragma unroll
        for (int c = 0; c < 4; c++) {
            o[c][0] *= alpha[0]; o[c][1] *= alpha[1];
            o[c][2] *= alpha[2]; o[c][3] *= alpha[3];
        }
        __syncthreads();   // P writes visible (lgkm drain) before A-layout reads
        short8 pf = *(const short8*)&myP[lane15 * 40 + quad * 8];
#pragma unroll
        for (int c = 0; c < 4; c++) {
            // V B-frag: lane holds V[key=kb+quad*8+j][d=c*16+lane15] = Vt[d][key]
            short8 vf = *(const short8*)&Vt[(size_t)(c * 16 + lane15) * 2048 + kb + quad * 8];
            o[c] = MFMA16(pf, vf, o[c]);
        }
        __syncthreads();   // WAR: all reads done before next iteration overwrites P
    }

#pragma unroll
    for (int c = 0; c < 4; c++)
#pragma unroll
        for (int r = 0; r < 4; r++) {
            float val = o[c][r] / l_run[r];
            attnout[(size_t)(b * 2048 + q0 + quad * 4 + r) * 1024 +
                    h * 64 + c * 16 + lane15] = f2b(val);
        }
}

extern "C" void kernel_launch(void* const* d_in, const int* in_sizes, int n_in,
                              void* d_out, int out_size, void* d_ws, size_t ws_size,
                              hipStream_t stream) {
    const float* x    = (const float*)d_in[0];
    const float* wq_w = (const float*)d_in[1];
    const float* wq_b = (const float*)d_in[2];
    const float* wk_w = (const float*)d_in[3];
    const float* wk_b = (const float*)d_in[4];
    const float* wv_w = (const float*)d_in[5];
    const float* wv_b = (const float*)d_in[6];
    const float* wo_w = (const float*)d_in[7];
    const float* wo_b = (const float*)d_in[8];
    float* out = (float*)d_out;

    char* ws = (char*)d_ws;
    size_t off = 0;
    unsigned short* xb      = (unsigned short*)(ws + off); off += (size_t)4096 * 1024 * 2;
    unsigned short* wqb     = (unsigned short*)(ws + off); off += (size_t)1024 * 1024 * 2;
    unsigned short* wkb     = (unsigned short*)(ws + off); off += (size_t)1024 * 1024 * 2;
    unsigned short* wvb     = (unsigned short*)(ws + off); off += (size_t)1024 * 1024 * 2;
    unsigned short* wob     = (unsigned short*)(ws + off); off += (size_t)1024 * 1024 * 2;
    unsigned short* qbuf    = (unsigned short*)(ws + off); off += (size_t)4096 * 1024 * 2;
    unsigned short* kbuf    = (unsigned short*)(ws + off); off += (size_t)4096 * 1024 * 2;
    unsigned short* vtbuf   = (unsigned short*)(ws + off); off += (size_t)4096 * 1024 * 2;
    unsigned short* attnout = (unsigned short*)(ws + off); off += (size_t)4096 * 1024 * 2;
    float* maskbuf          = (float*)(ws + off);          off += 4096 * 4;

    // fp32 -> bf16 conversions
    cvt_kernel<<<4096, 256, 0, stream>>>(x, xb, 1048576);
    cvt_kernel<<<1024, 256, 0, stream>>>(wq_w, wqb, 262144);
    cvt_kernel<<<1024, 256, 0, stream>>>(wk_w, wkb, 262144);
    cvt_kernel<<<1024, 256, 0, stream>>>(wv_w, wvb, 262144);
    cvt_kernel<<<1024, 256, 0, stream>>>(wo_w, wob, 262144);
    mask_kernel<<<16, 256, 0, stream>>>(x, maskbuf);

    dim3 ggrid(8, 32);  // N/128, M/128
    gemm_bt<<<ggrid, 256, 0, stream>>>(xb, wqb, wq_b, (void*)qbuf, 1);
    gemm_bt<<<ggrid, 256, 0, stream>>>(xb, wkb, wk_b, (void*)kbuf, 1);
    gemm_bt<<<ggrid, 256, 0, stream>>>(xb, wvb, wv_b, (void*)vtbuf, 2);

    attn_kernel<<<dim3(32, 16, 2), 256, 0, stream>>>(qbuf, kbuf, vtbuf, maskbuf, attnout);

    gemm_bt<<<ggrid, 256, 0, stream>>>(attnout, wob, wo_b, (void*)out, 0);
}

// Round 2
// 397.394 us; speedup vs baseline: 1.1331x; 1.1331x over previous
//
#include <hip/hip_runtime.h>
#include <hip/hip_bf16.h>

typedef short short8 __attribute__((ext_vector_type(8)));
typedef short short4v __attribute__((ext_vector_type(4)));
typedef float f32x4 __attribute__((ext_vector_type(4)));

#define MFMA32(a, b, c) __builtin_amdgcn_mfma_f32_16x16x32_bf16(a, b, c, 0, 0, 0)

#if __has_builtin(__builtin_amdgcn_mfma_f32_16x16x16bf16_1k)
#define MFMA16(a, b, c) __builtin_amdgcn_mfma_f32_16x16x16bf16_1k(a, b, c, 0, 0, 0)
#else
static __device__ __forceinline__ f32x4 MFMA16(short4v a, short4v b, f32x4 c) {
    asm volatile("v_mfma_f32_16x16x16_bf16 %0, %1, %2, %0\n\ts_nop 7\n\ts_nop 7"
                 : "+v"(c) : "v"(a), "v"(b));
    return c;
}
#endif

#if __has_builtin(__builtin_amdgcn_exp2f)
#define EXP2F(x) __builtin_amdgcn_exp2f(x)
#else
#define EXP2F(x) exp2f(x)
#endif

// async global->LDS, 16B per lane. LDS dest must be wave-uniform base + lane*16.
#define GLL16(gp, lp) __builtin_amdgcn_global_load_lds(                                  \
    (__attribute__((address_space(1))) unsigned int*)(unsigned long long)(const void*)(gp), \
    (__attribute__((address_space(3))) unsigned int*)(lp), 16, 0, 0)

// fp32 -> bf16 RNE
__device__ __forceinline__ unsigned short f2b(float f) {
    union { float f; unsigned int u; } v;
    v.f = f;
    unsigned int u = v.u;
    return (unsigned short)((u + 0x7fffu + ((u >> 16) & 1u)) >> 16);
}

// ---------------- x cvt + key mask ----------------
__global__ void cvt_x_mask(const float* __restrict__ x, unsigned short* __restrict__ xb,
                           float* __restrict__ maskbuf) {
    int i = blockIdx.x * 256 + threadIdx.x;   // 0..1048575 float4s
    float4 v = ((const float4*)x)[i];
    ushort4 o;
    o.x = f2b(v.x); o.y = f2b(v.y); o.z = f2b(v.z); o.w = f2b(v.w);
    ((ushort4*)xb)[i] = o;
    if ((i & 255) == 0)    // i*4 % 1024 == 0 -> first channel of token i>>8
        maskbuf[i >> 8] = (v.x != 0.0f) ? 0.0f : -1e30f;
}

// ---------------- 4 weights cvt ----------------
__global__ void cvt_w(const float* __restrict__ w0, const float* __restrict__ w1,
                      const float* __restrict__ w2, const float* __restrict__ w3,
                      unsigned short* __restrict__ wb) {
    int widx = blockIdx.x >> 10;
    int i = (blockIdx.x & 1023) * 256 + threadIdx.x;  // 0..262143 float4s
    const float* src = widx == 0 ? w0 : (widx == 1 ? w1 : (widx == 2 ? w2 : w3));
    float4 v = ((const float4*)src)[i];
    ushort4 o;
    o.x = f2b(v.x); o.y = f2b(v.y); o.z = f2b(v.z); o.w = f2b(v.w);
    ((ushort4*)(wb + ((size_t)widx << 20)))[i] = o;
}

// fold softmax scale (Dh^-0.5) and log2(e) into Q so attn uses raw exp2
#define QSCALE (0.125f * 1.44269504088896341f)

// ---------------- fused QKV GEMM (m97-style: global_load_lds staging) ----------------
// A: xb [4096,1024] bf16. grid (24, 32): blockIdx.x>>3 = seg (0=Q,1=K,2=V).
// Q,K out: (B,H,T,64) bf16 (Q pre-scaled). V out: (B,H,64,T) with key order permuted
// inside each 32-key group: pos = q*8 + t*4 + i  for key = 16t + 4q + i.
__global__ __launch_bounds__(256) void gemm_qkv(
        const unsigned short* __restrict__ A,
        const unsigned short* __restrict__ wq, const unsigned short* __restrict__ wk,
        const unsigned short* __restrict__ wv,
        const float* __restrict__ bq, const float* __restrict__ bk,
        const float* __restrict__ bv,
        unsigned short* __restrict__ qbuf, unsigned short* __restrict__ kbuf,
        unsigned short* __restrict__ vbuf) {
    __shared__ unsigned short As[128 * 32];
    __shared__ unsigned short Bs[128 * 32];
    int tid = threadIdx.x;
    int lane = tid & 63, wave = tid >> 6;
    int lane15 = lane & 15, quad = lane >> 4;
    int seg = blockIdx.x >> 3;
    int bn = (blockIdx.x & 7) * 128;
    int bm = blockIdx.y * 128;
    const unsigned short* Bw = seg == 0 ? wq : (seg == 1 ? wk : wv);
    const float* bias = seg == 0 ? bq : (seg == 1 ? bk : bv);
    int wm = (wave >> 1) * 64, wn = (wave & 1) * 64;

    f32x4 acc[4][4];
#pragma unroll
    for (int i = 0; i < 4; i++)
#pragma unroll
        for (int j = 0; j < 4; j++) acc[i][j] = (f32x4){0.f, 0.f, 0.f, 0.f};

    int arow = tid >> 2, acol = (tid & 3) * 8;
    for (int kb = 0; kb < 1024; kb += 32) {
        GLL16(&A[(size_t)(bm + arow) * 1024 + kb + acol],      &As[(size_t)tid * 8]);
        GLL16(&A[(size_t)(bm + 64 + arow) * 1024 + kb + acol], &As[(size_t)(tid + 256) * 8]);
        GLL16(&Bw[(size_t)(bn + arow) * 1024 + kb + acol],      &Bs[(size_t)tid * 8]);
        GLL16(&Bw[(size_t)(bn + 64 + arow) * 1024 + kb + acol], &Bs[(size_t)(tid + 256) * 8]);
        __syncthreads();
        short8 af[4], bf[4];
#pragma unroll
        for (int i = 0; i < 4; i++)
            af[i] = *(const short8*)&As[(wm + i * 16 + lane15) * 32 + quad * 8];
#pragma unroll
        for (int j = 0; j < 4; j++)
            bf[j] = *(const short8*)&Bs[(wn + j * 16 + lane15) * 32 + quad * 8];
#pragma unroll
        for (int i = 0; i < 4; i++)
#pragma unroll
            for (int j = 0; j < 4; j++)
                acc[i][j] = MFMA32(af[i], bf[j], acc[i][j]);
        __syncthreads();
    }

#pragma unroll
    for (int j = 0; j < 4; j++) {
        int nl = bn + wn + j * 16 + lane15;     // 0..1023
        int h = nl >> 6, d = nl & 63;
        float bv_ = bias[nl];
#pragma unroll
        for (int i = 0; i < 4; i++)
#pragma unroll
            for (int r = 0; r < 4; r++) {
                int m = bm + wm + i * 16 + quad * 4 + r;
                int b = m >> 11, tk = m & 2047;
                float v = acc[i][j][r] + bv_;
                if (seg == 0) {
                    qbuf[((size_t)((b * 16 + h) * 2048 + tk)) * 64 + d] = f2b(v * QSCALE);
                } else if (seg == 1) {
                    kbuf[((size_t)((b * 16 + h) * 2048 + tk)) * 64 + d] = f2b(v);
                } else {
                    int k5 = tk & 31, g = tk >> 5;
                    int pos = ((k5 >> 2) & 3) * 8 + ((k5 >> 4) << 2) + (k5 & 3);
                    vbuf[((size_t)((b * 16 + h) * 64 + d)) * 2048 + g * 32 + pos] = f2b(v);
                }
            }
    }
}

// ---------------- output projection GEMM (fp32 out) ----------------
__global__ __launch_bounds__(256) void gemm_proj(
        const unsigned short* __restrict__ A, const unsigned short* __restrict__ Bw,
        const float* __restrict__ bias, float* __restrict__ out) {
    __shared__ unsigned short As[128 * 32];
    __shared__ unsigned short Bs[128 * 32];
    int tid = threadIdx.x;
    int lane = tid & 63, wave = tid >> 6;
    int lane15 = lane & 15, quad = lane >> 4;
    int bn = blockIdx.x * 128, bm = blockIdx.y * 128;
    int wm = (wave >> 1) * 64, wn = (wave & 1) * 64;

    f32x4 acc[4][4];
#pragma unroll
    for (int i = 0; i < 4; i++)
#pragma unroll
        for (int j = 0; j < 4; j++) acc[i][j] = (f32x4){0.f, 0.f, 0.f, 0.f};

    int arow = tid >> 2, acol = (tid & 3) * 8;
    for (int kb = 0; kb < 1024; kb += 32) {
        GLL16(&A[(size_t)(bm + arow) * 1024 + kb + acol],      &As[(size_t)tid * 8]);
        GLL16(&A[(size_t)(bm + 64 + arow) * 1024 + kb + acol], &As[(size_t)(tid + 256) * 8]);
        GLL16(&Bw[(size_t)(bn + arow) * 1024 + kb + acol],      &Bs[(size_t)tid * 8]);
        GLL16(&Bw[(size_t)(bn + 64 + arow) * 1024 + kb + acol], &Bs[(size_t)(tid + 256) * 8]);
        __syncthreads();
        short8 af[4], bf[4];
#pragma unroll
        for (int i = 0; i < 4; i++)
            af[i] = *(const short8*)&As[(wm + i * 16 + lane15) * 32 + quad * 8];
#pragma unroll
        for (int j = 0; j < 4; j++)
            bf[j] = *(const short8*)&Bs[(wn + j * 16 + lane15) * 32 + quad * 8];
#pragma unroll
        for (int i = 0; i < 4; i++)
#pragma unroll
            for (int j = 0; j < 4; j++)
                acc[i][j] = MFMA32(af[i], bf[j], acc[i][j]);
        __syncthreads();
    }

#pragma unroll
    for (int j = 0; j < 4; j++) {
        int n = bn + wn + j * 16 + lane15;
        float bv_ = bias[n];
#pragma unroll
        for (int i = 0; i < 4; i++)
#pragma unroll
            for (int r = 0; r < 4; r++) {
                int m = bm + wm + i * 16 + quad * 4 + r;
                out[(size_t)m * 1024 + n] = acc[i][j][r] + bv_;
            }
    }
}

// ---------------- flash attention, S^T form, no LDS, no barriers ----------------
// grid (32,16,2), block 256 (4 waves, wave = 16 queries).
// S^T tile C-layout: col=lane15=query, row=quad*4+r=key  -> exactly the
// 16x16x16 PV B-operand layout B[k=quad*4+j][n=lane15]. Zero-movement P.
__global__ __launch_bounds__(256) void attn_kernel(
        const unsigned short* __restrict__ qbuf, const unsigned short* __restrict__ kbuf,
        const unsigned short* __restrict__ vbuf, const float* __restrict__ maskbuf,
        unsigned short* __restrict__ attnout) {
    int b = blockIdx.z, h = blockIdx.y, qt = blockIdx.x;
    int lane = threadIdx.x & 63, wave = threadIdx.x >> 6;
    int lane15 = lane & 15, quad = lane >> 4;
    int q0 = qt * 64 + wave * 16;

    const unsigned short* Q  = qbuf + (size_t)(b * 16 + h) * 2048 * 64;
    const unsigned short* Kp = kbuf + (size_t)(b * 16 + h) * 2048 * 64;
    const unsigned short* Vt = vbuf + (size_t)(b * 16 + h) * 64 * 2048;
    const float* mb = maskbuf + b * 2048;

    // Q as B-operand of 16x16x32: B[n=lane15][k=quad*8+j]
    short8 qf0 = *(const short8*)&Q[(size_t)(q0 + lane15) * 64 + quad * 8];
    short8 qf1 = *(const short8*)&Q[(size_t)(q0 + lane15) * 64 + 32 + quad * 8];

    float m_run = -1e30f, l_run = 0.f;
    f32x4 o[4];
#pragma unroll
    for (int c = 0; c < 4; c++) o[c] = (f32x4){0.f, 0.f, 0.f, 0.f};

    for (int kb = 0; kb < 2048; kb += 64) {
        // ---- S^T = K . Q^T over 4 key-16-tiles ----
        f32x4 s[4];
#pragma unroll
        for (int t = 0; t < 4; t++) {
            const unsigned short* kr = &Kp[(size_t)(kb + t * 16 + lane15) * 64];
            f32x4 st = (f32x4){0.f, 0.f, 0.f, 0.f};
            st = MFMA32(*(const short8*)&kr[quad * 8], qf0, st);
            st = MFMA32(*(const short8*)&kr[32 + quad * 8], qf1, st);
            s[t] = st;
        }
        // ---- masked scores (already in log2 domain via QSCALE) ----
        float v[16];
#pragma unroll
        for (int t = 0; t < 4; t++) {
            f32x4 mk = *(const f32x4*)&mb[kb + t * 16 + quad * 4];
#pragma unroll
            for (int r = 0; r < 4; r++) v[t * 4 + r] = s[t][r] + mk[r];
        }
        // ---- online softmax: in-register max + 2 shuffles ----
        float mx = v[0];
#pragma unroll
        for (int z = 1; z < 16; z++) mx = fmaxf(mx, v[z]);
        mx = fmaxf(mx, __shfl_xor(mx, 16));
        mx = fmaxf(mx, __shfl_xor(mx, 32));
        float mnew = fmaxf(m_run, mx);
        float alpha = EXP2F(m_run - mnew);
        m_run = mnew;
        float e[16], lsum = 0.f;
#pragma unroll
        for (int z = 0; z < 16; z++) { e[z] = EXP2F(v[z] - mnew); lsum += e[z]; }
        l_run = l_run * alpha + lsum;   // per-lane partial; reduced once at end
#pragma unroll
        for (int c = 0; c < 4; c++) o[c] *= alpha;
        // ---- P already in 16x16x16 B-layout: just pack to bf16 ----
        short4v pb[4];
#pragma unroll
        for (int t = 0; t < 4; t++) {
            short4v p;
            p[0] = (short)f2b(e[t * 4 + 0]);
            p[1] = (short)f2b(e[t * 4 + 1]);
            p[2] = (short)f2b(e[t * 4 + 2]);
            p[3] = (short)f2b(e[t * 4 + 3]);
            pb[t] = p;
        }
        // ---- O^T += V^T . P^T  (A-frags 16B-contiguous via permuted vbuf) ----
#pragma unroll
        for (int g = 0; g < 2; g++) {
#pragma unroll
            for (int c = 0; c < 4; c++) {
                short8 vv = *(const short8*)&Vt[(size_t)(c * 16 + lane15) * 2048 +
                                                kb + g * 32 + quad * 8];
                short4v v0 = __builtin_shufflevector(vv, vv, 0, 1, 2, 3);
                short4v v1 = __builtin_shufflevector(vv, vv, 4, 5, 6, 7);
                o[c] = MFMA16(v0, pb[2 * g + 0], o[c]);
                o[c] = MFMA16(v1, pb[2 * g + 1], o[c]);
            }
        }
    }

    // ---- epilogue: reduce l across quads once, scale, store O (row=query) ----
    l_run += __shfl_xor(l_run, 16);
    l_run += __shfl_xor(l_run, 32);
    float rl = 1.0f / l_run;
    size_t row = (size_t)(b * 2048 + q0 + lane15) * 1024 + h * 64 + quad * 4;
#pragma unroll
    for (int c = 0; c < 4; c++) {
        ushort4 pk;
        pk.x = f2b(o[c][0] * rl);
        pk.y = f2b(o[c][1] * rl);
        pk.z = f2b(o[c][2] * rl);
        pk.w = f2b(o[c][3] * rl);
        *(ushort4*)&attnout[row + c * 16] = pk;
    }
}

extern "C" void kernel_launch(void* const* d_in, const int* in_sizes, int n_in,
                              void* d_out, int out_size, void* d_ws, size_t ws_size,
                              hipStream_t stream) {
    const float* x    = (const float*)d_in[0];
    const float* wq_w = (const float*)d_in[1];
    const float* wq_b = (const float*)d_in[2];
    const float* wk_w = (const float*)d_in[3];
    const float* wk_b = (const float*)d_in[4];
    const float* wv_w = (const float*)d_in[5];
    const float* wv_b = (const float*)d_in[6];
    const float* wo_w = (const float*)d_in[7];
    const float* wo_b = (const float*)d_in[8];
    float* out = (float*)d_out;

    char* ws = (char*)d_ws;
    size_t off = 0;
    unsigned short* xb      = (unsigned short*)(ws + off); off += (size_t)4096 * 1024 * 2;
    unsigned short* wb      = (unsigned short*)(ws + off); off += (size_t)4 * 1024 * 1024 * 2;
    unsigned short* qbuf    = (unsigned short*)(ws + off); off += (size_t)4096 * 1024 * 2;
    unsigned short* kbuf    = (unsigned short*)(ws + off); off += (size_t)4096 * 1024 * 2;
    unsigned short* vbuf    = (unsigned short*)(ws + off); off += (size_t)4096 * 1024 * 2;
    unsigned short* attnout = (unsigned short*)(ws + off); off += (size_t)4096 * 1024 * 2;
    float* maskbuf          = (float*)(ws + off);          off += 4096 * 4;

    unsigned short* wqb = wb;
    unsigned short* wkb = wb + (1u << 20);
    unsigned short* wvb = wb + (2u << 20);
    unsigned short* wob = wb + (3u << 20);

    cvt_x_mask<<<4096, 256, 0, stream>>>(x, xb, maskbuf);
    cvt_w<<<4096, 256, 0, stream>>>(wq_w, wk_w, wv_w, wo_w, wb);

    gemm_qkv<<<dim3(24, 32), 256, 0, stream>>>(xb, wqb, wkb, wvb,
                                               wq_b, wk_b, wv_b, qbuf, kbuf, vbuf);

    attn_kernel<<<dim3(32, 16, 2), 256, 0, stream>>>(qbuf, kbuf, vbuf, maskbuf, attnout);

    gemm_proj<<<dim3(8, 32), 256, 0, stream>>>(attnout, wob, wo_b, out);
}

// Round 3
// 240.400 us; speedup vs baseline: 1.8731x; 1.6530x over previous
//
#include <hip/hip_runtime.h>
#include <hip/hip_bf16.h>

typedef short short8 __attribute__((ext_vector_type(8)));
typedef short short4v __attribute__((ext_vector_type(4)));
typedef float f32x4 __attribute__((ext_vector_type(4)));
typedef unsigned int uint2v __attribute__((ext_vector_type(2)));

#define MFMA32(a, b, c) __builtin_amdgcn_mfma_f32_16x16x32_bf16(a, b, c, 0, 0, 0)

#if __has_builtin(__builtin_amdgcn_mfma_f32_16x16x16bf16_1k)
#define MFMA16(a, b, c) __builtin_amdgcn_mfma_f32_16x16x16bf16_1k(a, b, c, 0, 0, 0)
#else
static __device__ __forceinline__ f32x4 MFMA16(short4v a, short4v b, f32x4 c) {
    asm volatile("v_mfma_f32_16x16x16_bf16 %0, %1, %2, %0\n\ts_nop 7\n\ts_nop 7"
                 : "+v"(c) : "v"(a), "v"(b));
    return c;
}
#endif

#if __has_builtin(__builtin_amdgcn_exp2f)
#define EXP2F(x) __builtin_amdgcn_exp2f(x)
#else
#define EXP2F(x) exp2f(x)
#endif

// async global->LDS, 16B per lane; LDS dest = wave-uniform base + lane*16
#define GLL16(gp, lp) __builtin_amdgcn_global_load_lds(                                  \
    (__attribute__((address_space(1))) unsigned int*)(unsigned long long)(const void*)(gp), \
    (__attribute__((address_space(3))) unsigned int*)(lp), 16, 0, 0)

// fp32 -> bf16 RNE
__device__ __forceinline__ unsigned short f2b(float f) {
    union { float f; unsigned int u; } v;
    v.f = f;
    unsigned int u = v.u;
    return (unsigned short)((u + 0x7fffu + ((u >> 16) & 1u)) >> 16);
}

static __device__ __forceinline__ f32x4 max4(f32x4 x, f32x4 y) {
    f32x4 r;
    r[0] = fmaxf(x[0], y[0]); r[1] = fmaxf(x[1], y[1]);
    r[2] = fmaxf(x[2], y[2]); r[3] = fmaxf(x[3], y[3]);
    return r;
}

// ---------------- x cvt + key mask ----------------
__global__ void cvt_x_mask(const float* __restrict__ x, unsigned short* __restrict__ xb,
                           float* __restrict__ maskbuf) {
    int i = blockIdx.x * 256 + threadIdx.x;   // 0..1048575 float4s
    float4 v = ((const float4*)x)[i];
    ushort4 o;
    o.x = f2b(v.x); o.y = f2b(v.y); o.z = f2b(v.z); o.w = f2b(v.w);
    ((ushort4*)xb)[i] = o;
    if ((i & 255) == 0)
        maskbuf[i >> 8] = (v.x != 0.0f) ? 0.0f : -1e30f;
}

// ---------------- 4 weights cvt ----------------
__global__ void cvt_w(const float* __restrict__ w0, const float* __restrict__ w1,
                      const float* __restrict__ w2, const float* __restrict__ w3,
                      unsigned short* __restrict__ wb) {
    int widx = blockIdx.x >> 10;
    int i = (blockIdx.x & 1023) * 256 + threadIdx.x;
    const float* src = widx == 0 ? w0 : (widx == 1 ? w1 : (widx == 2 ? w2 : w3));
    float4 v = ((const float4*)src)[i];
    ushort4 o;
    o.x = f2b(v.x); o.y = f2b(v.y); o.z = f2b(v.z); o.w = f2b(v.w);
    ((ushort4*)(wb + ((size_t)widx << 20)))[i] = o;
}

// fold softmax scale (Dh^-0.5) and log2(e) into Q so attn uses raw exp2
#define QSCALE (0.125f * 1.44269504088896341f)

// ---------------- fused QKV GEMM ----------------
// grid (24, 32): blockIdx.x>>3 = seg (0=Q,1=K,2=V). Q,K out: (B,H,T,64) bf16
// (Q pre-scaled). V out: (B,H,64,Tperm), pos = q*8 + t*4 + i for key 16t+4q+i
// within each 32-key group (so one b128 = two MFMA16 A-frags in attn).
__global__ __launch_bounds__(256) void gemm_qkv(
        const unsigned short* __restrict__ A,
        const unsigned short* __restrict__ wq, const unsigned short* __restrict__ wk,
        const unsigned short* __restrict__ wv,
        const float* __restrict__ bq, const float* __restrict__ bk,
        const float* __restrict__ bv,
        unsigned short* __restrict__ qbuf, unsigned short* __restrict__ kbuf,
        unsigned short* __restrict__ vbuf) {
    __shared__ unsigned short As[128 * 32];
    __shared__ unsigned short Bs[128 * 32];
    int tid = threadIdx.x;
    int lane = tid & 63, wave = tid >> 6;
    int lane15 = lane & 15, quad = lane >> 4;
    int seg = blockIdx.x >> 3;
    int bn = (blockIdx.x & 7) * 128;
    int bm = blockIdx.y * 128;
    const unsigned short* Bw = seg == 0 ? wq : (seg == 1 ? wk : wv);
    const float* bias = seg == 0 ? bq : (seg == 1 ? bk : bv);
    int wm = (wave >> 1) * 64, wn = (wave & 1) * 64;

    f32x4 acc[4][4];
#pragma unroll
    for (int i = 0; i < 4; i++)
#pragma unroll
        for (int j = 0; j < 4; j++) acc[i][j] = (f32x4){0.f, 0.f, 0.f, 0.f};

    int arow = tid >> 2, acol = (tid & 3) * 8;
    for (int kb = 0; kb < 1024; kb += 32) {
        GLL16(&A[(size_t)(bm + arow) * 1024 + kb + acol],      &As[(size_t)tid * 8]);
        GLL16(&A[(size_t)(bm + 64 + arow) * 1024 + kb + acol], &As[(size_t)(tid + 256) * 8]);
        GLL16(&Bw[(size_t)(bn + arow) * 1024 + kb + acol],      &Bs[(size_t)tid * 8]);
        GLL16(&Bw[(size_t)(bn + 64 + arow) * 1024 + kb + acol], &Bs[(size_t)(tid + 256) * 8]);
        __syncthreads();
        short8 af[4], bf[4];
#pragma unroll
        for (int i = 0; i < 4; i++)
            af[i] = *(const short8*)&As[(wm + i * 16 + lane15) * 32 + quad * 8];
#pragma unroll
        for (int j = 0; j < 4; j++)
            bf[j] = *(const short8*)&Bs[(wn + j * 16 + lane15) * 32 + quad * 8];
#pragma unroll
        for (int i = 0; i < 4; i++)
#pragma unroll
            for (int j = 0; j < 4; j++)
                acc[i][j] = MFMA32(af[i], bf[j], acc[i][j]);
        __syncthreads();
    }

    int bb = bm >> 11;
#pragma unroll
    for (int j = 0; j < 4; j++) {
        int nl = bn + wn + j * 16 + lane15;     // 0..1023
        int h = nl >> 6, d = nl & 63;
        float bv_ = bias[nl];
        if (seg == 2) {
            size_t vbase = ((size_t)((bb * 16 + h) * 64 + d)) * 2048;
#pragma unroll
            for (int i = 0; i < 4; i++) {
                int tk0 = (bm & 2047) + wm + i * 16 + quad * 4;
                int grp = tk0 >> 5;
                ushort4 pk;
                pk.x = f2b(acc[i][j][0] + bv_);
                pk.y = f2b(acc[i][j][1] + bv_);
                pk.z = f2b(acc[i][j][2] + bv_);
                pk.w = f2b(acc[i][j][3] + bv_);
                *(ushort4*)&vbuf[vbase + grp * 32 + quad * 8 + (i & 1) * 4] = pk;
            }
        } else {
#pragma unroll
            for (int i = 0; i < 4; i++)
#pragma unroll
                for (int r = 0; r < 4; r++) {
                    int m = bm + wm + i * 16 + quad * 4 + r;
                    int tk = m & 2047;
                    float v = acc[i][j][r] + bv_;
                    size_t off = ((size_t)((bb * 16 + h) * 2048 + tk)) * 64 + d;
                    if (seg == 0) qbuf[off] = f2b(v * QSCALE);
                    else          kbuf[off] = f2b(v);
                }
        }
    }
}

// ---------------- output projection GEMM (fp32 out) ----------------
__global__ __launch_bounds__(256) void gemm_proj(
        const unsigned short* __restrict__ A, const unsigned short* __restrict__ Bw,
        const float* __restrict__ bias, float* __restrict__ out) {
    __shared__ unsigned short As[128 * 32];
    __shared__ unsigned short Bs[128 * 32];
    int tid = threadIdx.x;
    int lane = tid & 63, wave = tid >> 6;
    int lane15 = lane & 15, quad = lane >> 4;
    int bn = blockIdx.x * 128, bm = blockIdx.y * 128;
    int wm = (wave >> 1) * 64, wn = (wave & 1) * 64;

    f32x4 acc[4][4];
#pragma unroll
    for (int i = 0; i < 4; i++)
#pragma unroll
        for (int j = 0; j < 4; j++) acc[i][j] = (f32x4){0.f, 0.f, 0.f, 0.f};

    int arow = tid >> 2, acol = (tid & 3) * 8;
    for (int kb = 0; kb < 1024; kb += 32) {
        GLL16(&A[(size_t)(bm + arow) * 1024 + kb + acol],      &As[(size_t)tid * 8]);
        GLL16(&A[(size_t)(bm + 64 + arow) * 1024 + kb + acol], &As[(size_t)(tid + 256) * 8]);
        GLL16(&Bw[(size_t)(bn + arow) * 1024 + kb + acol],      &Bs[(size_t)tid * 8]);
        GLL16(&Bw[(size_t)(bn + 64 + arow) * 1024 + kb + acol], &Bs[(size_t)(tid + 256) * 8]);
        __syncthreads();
        short8 af[4], bf[4];
#pragma unroll
        for (int i = 0; i < 4; i++)
            af[i] = *(const short8*)&As[(wm + i * 16 + lane15) * 32 + quad * 8];
#pragma unroll
        for (int j = 0; j < 4; j++)
            bf[j] = *(const short8*)&Bs[(wn + j * 16 + lane15) * 32 + quad * 8];
#pragma unroll
        for (int i = 0; i < 4; i++)
#pragma unroll
            for (int j = 0; j < 4; j++)
                acc[i][j] = MFMA32(af[i], bf[j], acc[i][j]);
        __syncthreads();
    }

#pragma unroll
    for (int j = 0; j < 4; j++) {
        int n = bn + wn + j * 16 + lane15;
        float bv_ = bias[n];
#pragma unroll
        for (int i = 0; i < 4; i++)
#pragma unroll
            for (int r = 0; r < 4; r++) {
                int m = bm + wm + i * 16 + quad * 4 + r;
                out[(size_t)m * 1024 + n] = acc[i][j][r] + bv_;
            }
    }
}

// ---------------- flash attention v3 ----------------
// 512 blocks 1D (XCD-swizzled), 256 threads = 4 waves, 32 queries/wave.
// Per 128-key iter: K,V tiles cooperatively staged to LDS via global_load_lds
// (XOR chunk swizzle for conflict-free ds_read_b128), S^T C-layout == PV
// B-operand layout (zero-movement P), online softmax in registers.
__global__ __launch_bounds__(256, 2) void attn_kernel(
        const unsigned short* __restrict__ qbuf, const unsigned short* __restrict__ kbuf,
        const unsigned short* __restrict__ vtbuf, const float* __restrict__ maskbuf,
        unsigned short* __restrict__ attnout) {
    __shared__ unsigned short Ks[128 * 64];   // key-row major, 8x16B chunks, XOR-swizzled
    __shared__ unsigned short Vs[64 * 128];   // d-row major, 16x16B chunks, XOR-swizzled

    int id = blockIdx.x;
    int combo = (id & 7) | (((id >> 7) & 3) << 3);   // same-combo blocks -> same XCD
    int qt = (id >> 3) & 15;
    int b = combo >> 4, h = combo & 15;
    int tid = threadIdx.x, lane = tid & 63, wave = tid >> 6;
    int lane15 = lane & 15, quad = lane >> 4;
    int q0 = qt * 128 + wave * 32;

    const unsigned short* Q  = qbuf  + (size_t)combo * 2048 * 64;
    const unsigned short* Kp = kbuf  + (size_t)combo * 2048 * 64;
    const unsigned short* Vt = vtbuf + (size_t)combo * 64 * 2048;
    const float* mb = maskbuf + b * 2048;

    // Q as 16x16x32 B-operand: B[n=lane15][k=quad*8+j]; two 16-q tiles, two k-halves
    short8 qf[2][2];
#pragma unroll
    for (int a = 0; a < 2; a++)
#pragma unroll
        for (int g = 0; g < 2; g++)
            qf[a][g] = *(const short8*)&Q[(size_t)(q0 + a * 16 + lane15) * 64 + g * 32 + quad * 8];

    float m_run[2] = {-1e30f, -1e30f}, l_run[2] = {0.f, 0.f};
    f32x4 o[2][4];
#pragma unroll
    for (int a = 0; a < 2; a++)
#pragma unroll
        for (int c = 0; c < 4; c++) o[a][c] = (f32x4){0.f, 0.f, 0.f, 0.f};

    const f32x4 z4 = {0.f, 0.f, 0.f, 0.f};
    int x7 = lane15 & 7;

    for (int kb = 0; kb < 2048; kb += 128) {
        // ---- cooperative staging: K 16KB + V 16KB, 8 GLL16/thread ----
#pragma unroll
        for (int r4 = 0; r4 < 4; r4++) {
            int ci = tid + r4 * 256;                  // 0..1023 16B-chunks
            int kr = ci >> 3, kc = (ci & 7) ^ (kr & 7);
            GLL16(&Kp[(size_t)(kb + kr) * 64 + kc * 8], &Ks[(size_t)ci * 8]);
            int vd = ci >> 4, vc = (ci & 15) ^ (vd & 15);
            GLL16(&Vt[(size_t)vd * 2048 + kb + vc * 8], &Vs[(size_t)ci * 8]);
        }
        __syncthreads();

        // ---- S^T = K.Q^T : 8 key-tiles x 2 q-tiles ----
        f32x4 s[2][8];
#pragma unroll
        for (int t = 0; t < 8; t++) {
            int row = t * 16 + lane15;
            short8 k0 = *(const short8*)&Ks[row * 64 + (quad ^ x7) * 8];
            short8 k1 = *(const short8*)&Ks[row * 64 + ((quad + 4) ^ x7) * 8];
            f32x4 t0 = MFMA32(k0, qf[0][0], z4);
            s[0][t] = MFMA32(k1, qf[0][1], t0);
            f32x4 t1 = MFMA32(k0, qf[1][0], z4);
            s[1][t] = MFMA32(k1, qf[1][1], t1);
        }
        // ---- mask (additive -1e30, scores in log2 domain) ----
#pragma unroll
        for (int t = 0; t < 8; t++) {
            f32x4 mkt = *(const f32x4*)&mb[kb + t * 16 + quad * 4];
            s[0][t] += mkt;
            s[1][t] += mkt;
        }
        // ---- online softmax + P pack (per q-tile) ----
        short4v pb[2][8];
#pragma unroll
        for (int a = 0; a < 2; a++) {
            f32x4 m4 = s[a][0];
#pragma unroll
            for (int t = 1; t < 8; t++) m4 = max4(m4, s[a][t]);
            float mx = fmaxf(fmaxf(m4[0], m4[1]), fmaxf(m4[2], m4[3]));
            mx = fmaxf(mx, __shfl_xor(mx, 16));
            mx = fmaxf(mx, __shfl_xor(mx, 32));
            float mnew = fmaxf(m_run[a], mx);
            float alpha = EXP2F(m_run[a] - mnew);
            m_run[a] = mnew;
            float ls = 0.f;
#pragma unroll
            for (int t = 0; t < 8; t++) {
                float e0 = EXP2F(s[a][t][0] - mnew);
                float e1 = EXP2F(s[a][t][1] - mnew);
                float e2 = EXP2F(s[a][t][2] - mnew);
                float e3 = EXP2F(s[a][t][3] - mnew);
                ls += (e0 + e1) + (e2 + e3);
                // bf16 truncation pack via v_perm (P in [0,1]; RTZ ok)
                union { uint2v u; short4v sv; } pu;
                pu.u[0] = __builtin_amdgcn_perm(__float_as_uint(e1), __float_as_uint(e0),
                                                0x07060302u);
                pu.u[1] = __builtin_amdgcn_perm(__float_as_uint(e3), __float_as_uint(e2),
                                                0x07060302u);
                pb[a][t] = pu.sv;
            }
            l_run[a] = l_run[a] * alpha + ls;
#pragma unroll
            for (int c = 0; c < 4; c++) o[a][c] *= alpha;
        }
        // ---- O^T += V^T.P^T : one b128 = two MFMA16 A-frags, shared by both q-tiles ----
#pragma unroll
        for (int c = 0; c < 4; c++) {
            int d = c * 16 + lane15;
#pragma unroll
            for (int g = 0; g < 4; g++) {
                int skc = (g * 4 + quad) ^ lane15;
                short8 vv = *(const short8*)&Vs[d * 128 + skc * 8];
                short4v v0 = __builtin_shufflevector(vv, vv, 0, 1, 2, 3);
                short4v v1 = __builtin_shufflevector(vv, vv, 4, 5, 6, 7);
                o[0][c] = MFMA16(v0, pb[0][2 * g],     o[0][c]);
                o[0][c] = MFMA16(v1, pb[0][2 * g + 1], o[0][c]);
                o[1][c] = MFMA16(v0, pb[1][2 * g],     o[1][c]);
                o[1][c] = MFMA16(v1, pb[1][2 * g + 1], o[1][c]);
            }
        }
        __syncthreads();   // WAR before next staging round
    }

    // ---- epilogue ----
#pragma unroll
    for (int a = 0; a < 2; a++) {
        float l = l_run[a];
        l += __shfl_xor(l, 16);
        l += __shfl_xor(l, 32);
        float rl = 1.0f / l;
        size_t row = (size_t)(b * 2048 + q0 + a * 16 + lane15) * 1024 + h * 64 + quad * 4;
#pragma unroll
        for (int c = 0; c < 4; c++) {
            ushort4 pk;
            pk.x = f2b(o[a][c][0] * rl);
            pk.y = f2b(o[a][c][1] * rl);
            pk.z = f2b(o[a][c][2] * rl);
            pk.w = f2b(o[a][c][3] * rl);
            *(ushort4*)&attnout[row + c * 16] = pk;
        }
    }
}

extern "C" void kernel_launch(void* const* d_in, const int* in_sizes, int n_in,
                              void* d_out, int out_size, void* d_ws, size_t ws_size,
                              hipStream_t stream) {
    const float* x    = (const float*)d_in[0];
    const float* wq_w = (const float*)d_in[1];
    const float* wq_b = (const float*)d_in[2];
    const float* wk_w = (const float*)d_in[3];
    const float* wk_b = (const float*)d_in[4];
    const float* wv_w = (const float*)d_in[5];
    const float* wv_b = (const float*)d_in[6];
    const float* wo_w = (const float*)d_in[7];
    const float* wo_b = (const float*)d_in[8];
    float* out = (float*)d_out;

    char* ws = (char*)d_ws;
    size_t off = 0;
    unsigned short* xb      = (unsigned short*)(ws + off); off += (size_t)4096 * 1024 * 2;
    unsigned short* wb      = (unsigned short*)(ws + off); off += (size_t)4 * 1024 * 1024 * 2;
    unsigned short* qbuf    = (unsigned short*)(ws + off); off += (size_t)4096 * 1024 * 2;
    unsigned short* kbuf    = (unsigned short*)(ws + off); off += (size_t)4096 * 1024 * 2;
    unsigned short* vbuf    = (unsigned short*)(ws + off); off += (size_t)4096 * 1024 * 2;
    unsigned short* attnout = (unsigned short*)(ws + off); off += (size_t)4096 * 1024 * 2;
    float* maskbuf          = (float*)(ws + off);          off += 4096 * 4;

    unsigned short* wqb = wb;
    unsigned short* wkb = wb + (1u << 20);
    unsigned short* wvb = wb + (2u << 20);
    unsigned short* wob = wb + (3u << 20);

    cvt_x_mask<<<4096, 256, 0, stream>>>(x, xb, maskbuf);
    cvt_w<<<4096, 256, 0, stream>>>(wq_w, wk_w, wv_w, wo_w, wb);

    gemm_qkv<<<dim3(24, 32), 256, 0, stream>>>(xb, wqb, wkb, wvb,
                                               wq_b, wk_b, wv_b, qbuf, kbuf, vbuf);

    attn_kernel<<<512, 256, 0, stream>>>(qbuf, kbuf, vbuf, maskbuf, attnout);

    gemm_proj<<<dim3(8, 32), 256, 0, stream>>>(attnout, wob, wo_b, out);
}

// Round 4
// 218.780 us; speedup vs baseline: 2.0582x; 1.0988x over previous
//
#include <hip/hip_runtime.h>
#include <hip/hip_bf16.h>

typedef short short8 __attribute__((ext_vector_type(8)));
typedef float f32x4 __attribute__((ext_vector_type(4)));

#define MFMA32(a, b, c) __builtin_amdgcn_mfma_f32_16x16x32_bf16(a, b, c, 0, 0, 0)

#if __has_builtin(__builtin_amdgcn_exp2f)
#define EXP2F(x) __builtin_amdgcn_exp2f(x)
#else
#define EXP2F(x) exp2f(x)
#endif

// async global->LDS, 16B per lane; LDS dest = wave-uniform base + lane*16
#define GLL16(gp, lp) __builtin_amdgcn_global_load_lds(                                  \
    (__attribute__((address_space(1))) unsigned int*)(unsigned long long)(const void*)(gp), \
    (__attribute__((address_space(3))) unsigned int*)(lp), 16, 0, 0)

// fp32 -> bf16 RNE
__device__ __forceinline__ unsigned short f2b(float f) {
    union { float f; unsigned int u; } v;
    v.f = f;
    unsigned int u = v.u;
    return (unsigned short)((u + 0x7fffu + ((u >> 16) & 1u)) >> 16);
}

static __device__ __forceinline__ f32x4 max4(f32x4 x, f32x4 y) {
    f32x4 r;
    r[0] = fmaxf(x[0], y[0]); r[1] = fmaxf(x[1], y[1]);
    r[2] = fmaxf(x[2], y[2]); r[3] = fmaxf(x[3], y[3]);
    return r;
}

// ---------------- merged cvt: x (+mask) and 4 weights ----------------
__global__ void cvt_all(const float* __restrict__ x,
                        const float* __restrict__ w0, const float* __restrict__ w1,
                        const float* __restrict__ w2, const float* __restrict__ w3,
                        unsigned short* __restrict__ xb, unsigned short* __restrict__ wb,
                        float* __restrict__ maskbuf) {
    int blk = blockIdx.x;
    if (blk < 4096) {
        int i = blk * 256 + threadIdx.x;           // 0..1048575 float4s
        float4 v = ((const float4*)x)[i];
        ushort4 o;
        o.x = f2b(v.x); o.y = f2b(v.y); o.z = f2b(v.z); o.w = f2b(v.w);
        ((ushort4*)xb)[i] = o;
        if ((i & 255) == 0)
            maskbuf[i >> 8] = (v.x != 0.0f) ? 0.0f : -1e30f;
    } else {
        int wi = blk - 4096;
        int widx = wi >> 10;
        int i = (wi & 1023) * 256 + threadIdx.x;   // 0..262143 float4s
        const float* src = widx == 0 ? w0 : (widx == 1 ? w1 : (widx == 2 ? w2 : w3));
        float4 v = ((const float4*)src)[i];
        ushort4 o;
        o.x = f2b(v.x); o.y = f2b(v.y); o.z = f2b(v.z); o.w = f2b(v.w);
        ((ushort4*)(wb + ((size_t)widx << 20)))[i] = o;
    }
}

// fold softmax scale (Dh^-0.5) and log2(e) into Q so attn uses raw exp2
#define QSCALE (0.125f * 1.44269504088896341f)

// ---------------- fused QKV GEMM, double-buffered, 1 barrier/iter ----------------
// grid (24, 32): blockIdx.x>>3 = seg (0=Q,1=K,2=V). Q,K out: (B,H,T,64) bf16
// (Q pre-scaled). V out: (B,H,64,Tperm), pos = q*8 + t*4 + i for key 16t+4q+i
// within each 32-key group (one b128 = MFMA32 A-frag in attn).
__global__ __launch_bounds__(256) void gemm_qkv(
        const unsigned short* __restrict__ A,
        const unsigned short* __restrict__ wq, const unsigned short* __restrict__ wk,
        const unsigned short* __restrict__ wv,
        const float* __restrict__ bq, const float* __restrict__ bk,
        const float* __restrict__ bv,
        unsigned short* __restrict__ qbuf, unsigned short* __restrict__ kbuf,
        unsigned short* __restrict__ vbuf) {
    __shared__ __attribute__((aligned(16))) unsigned short As[2][128 * 32];
    __shared__ __attribute__((aligned(16))) unsigned short Bs[2][128 * 32];
    int tid = threadIdx.x;
    int lane = tid & 63, wave = tid >> 6;
    int lane15 = lane & 15, quad = lane >> 4;
    int seg = blockIdx.x >> 3;
    int bn = (blockIdx.x & 7) * 128;
    int bm = blockIdx.y * 128;
    const unsigned short* Bw = seg == 0 ? wq : (seg == 1 ? wk : wv);
    const float* bias = seg == 0 ? bq : (seg == 1 ? bk : bv);
    int wm = (wave >> 1) * 64, wn = (wave & 1) * 64;

    f32x4 acc[4][4];
#pragma unroll
    for (int i = 0; i < 4; i++)
#pragma unroll
        for (int j = 0; j < 4; j++) acc[i][j] = (f32x4){0.f, 0.f, 0.f, 0.f};

    int arow = tid >> 2, acol = (tid & 3) * 8;
    const unsigned short* A0 = &A[(size_t)(bm + arow) * 1024 + acol];
    const unsigned short* A1 = A0 + (size_t)64 * 1024;
    const unsigned short* B0 = &Bw[(size_t)(bn + arow) * 1024 + acol];
    const unsigned short* B1 = B0 + (size_t)64 * 1024;

    // prologue: stage k-tile 0 into buffer 0
    GLL16(A0, &As[0][(size_t)tid * 8]);
    GLL16(A1, &As[0][(size_t)(tid + 256) * 8]);
    GLL16(B0, &Bs[0][(size_t)tid * 8]);
    GLL16(B1, &Bs[0][(size_t)(tid + 256) * 8]);

    for (int it = 0; it < 32; it++) {
        int cur = it & 1;
        __syncthreads();                 // tile[cur] ready; prior reads drained
        if (it < 31) {                   // prefetch tile[cur^1]
            int kn = (it + 1) * 32;
            GLL16(A0 + kn, &As[cur ^ 1][(size_t)tid * 8]);
            GLL16(A1 + kn, &As[cur ^ 1][(size_t)(tid + 256) * 8]);
            GLL16(B0 + kn, &Bs[cur ^ 1][(size_t)tid * 8]);
            GLL16(B1 + kn, &Bs[cur ^ 1][(size_t)(tid + 256) * 8]);
        }
        const unsigned short* as = As[cur];
        const unsigned short* bs = Bs[cur];
        short8 af[4], bf[4];
#pragma unroll
        for (int i = 0; i < 4; i++)
            af[i] = *(const short8*)&as[(wm + i * 16 + lane15) * 32 + quad * 8];
#pragma unroll
        for (int j = 0; j < 4; j++)
            bf[j] = *(const short8*)&bs[(wn + j * 16 + lane15) * 32 + quad * 8];
#pragma unroll
        for (int i = 0; i < 4; i++)
#pragma unroll
            for (int j = 0; j < 4; j++)
                acc[i][j] = MFMA32(af[i], bf[j], acc[i][j]);
    }

    int bb = bm >> 11;
#pragma unroll
    for (int j = 0; j < 4; j++) {
        int nl = bn + wn + j * 16 + lane15;     // 0..1023
        int h = nl >> 6, d = nl & 63;
        float bv_ = bias[nl];
        if (seg == 2) {
            size_t vbase = ((size_t)((bb * 16 + h) * 64 + d)) * 2048;
#pragma unroll
            for (int i = 0; i < 4; i++) {
                int tk0 = (bm & 2047) + wm + i * 16 + quad * 4;
                int grp = tk0 >> 5;
                ushort4 pk;
                pk.x = f2b(acc[i][j][0] + bv_);
                pk.y = f2b(acc[i][j][1] + bv_);
                pk.z = f2b(acc[i][j][2] + bv_);
                pk.w = f2b(acc[i][j][3] + bv_);
                *(ushort4*)&vbuf[vbase + grp * 32 + quad * 8 + (i & 1) * 4] = pk;
            }
        } else {
#pragma unroll
            for (int i = 0; i < 4; i++)
#pragma unroll
                for (int r = 0; r < 4; r++) {
                    int m = bm + wm + i * 16 + quad * 4 + r;
                    int tk = m & 2047;
                    float v = acc[i][j][r] + bv_;
                    size_t off = ((size_t)((bb * 16 + h) * 2048 + tk)) * 64 + d;
                    if (seg == 0) qbuf[off] = f2b(v * QSCALE);
                    else          kbuf[off] = f2b(v);
                }
        }
    }
}

// ---------------- output projection GEMM: 64x128 tiles, dbuf, fp32 out ----------------
// grid (8, 64) = 512 blocks (2/CU). Wave tile 32x64.
__global__ __launch_bounds__(256) void gemm_proj(
        const unsigned short* __restrict__ A, const unsigned short* __restrict__ Bw,
        const float* __restrict__ bias, float* __restrict__ out) {
    __shared__ __attribute__((aligned(16))) unsigned short As[2][64 * 32];
    __shared__ __attribute__((aligned(16))) unsigned short Bs[2][128 * 32];
    int tid = threadIdx.x;
    int lane = tid & 63, wave = tid >> 6;
    int lane15 = lane & 15, quad = lane >> 4;
    int bn = blockIdx.x * 128, bm = blockIdx.y * 64;
    int wm = (wave >> 1) * 32, wn = (wave & 1) * 64;

    f32x4 acc[2][4];
#pragma unroll
    for (int i = 0; i < 2; i++)
#pragma unroll
        for (int j = 0; j < 4; j++) acc[i][j] = (f32x4){0.f, 0.f, 0.f, 0.f};

    int arow = tid >> 2, acol = (tid & 3) * 8;
    const unsigned short* A0 = &A[(size_t)(bm + arow) * 1024 + acol];
    const unsigned short* B0 = &Bw[(size_t)(bn + arow) * 1024 + acol];
    const unsigned short* B1 = B0 + (size_t)64 * 1024;

    GLL16(A0, &As[0][(size_t)tid * 8]);
    GLL16(B0, &Bs[0][(size_t)tid * 8]);
    GLL16(B1, &Bs[0][(size_t)(tid + 256) * 8]);

    for (int it = 0; it < 32; it++) {
        int cur = it & 1;
        __syncthreads();
        if (it < 31) {
            int kn = (it + 1) * 32;
            GLL16(A0 + kn, &As[cur ^ 1][(size_t)tid * 8]);
            GLL16(B0 + kn, &Bs[cur ^ 1][(size_t)tid * 8]);
            GLL16(B1 + kn, &Bs[cur ^ 1][(size_t)(tid + 256) * 8]);
        }
        const unsigned short* as = As[cur];
        const unsigned short* bs = Bs[cur];
        short8 af[2], bf[4];
#pragma unroll
        for (int i = 0; i < 2; i++)
            af[i] = *(const short8*)&as[(wm + i * 16 + lane15) * 32 + quad * 8];
#pragma unroll
        for (int j = 0; j < 4; j++)
            bf[j] = *(const short8*)&bs[(wn + j * 16 + lane15) * 32 + quad * 8];
#pragma unroll
        for (int i = 0; i < 2; i++)
#pragma unroll
            for (int j = 0; j < 4; j++)
                acc[i][j] = MFMA32(af[i], bf[j], acc[i][j]);
    }

#pragma unroll
    for (int j = 0; j < 4; j++) {
        int n = bn + wn + j * 16 + lane15;
        float bv_ = bias[n];
#pragma unroll
        for (int i = 0; i < 2; i++)
#pragma unroll
            for (int r = 0; r < 4; r++) {
                int m = bm + wm + i * 16 + quad * 4 + r;
                out[(size_t)m * 1024 + n] = acc[i][j][r] + bv_;
            }
    }
}

// ---------------- flash attention v4: dbuf LDS, 1 barrier/iter, all-MFMA32 ----------------
// 512 blocks 1D (XCD-swizzled), 256 threads = 4 waves, 32 queries/wave.
// S^T C-layout (col=query=lane15, row=key) + permuted V order means the exp'd
// scores of two 16-key tiles concatenate into the exact 16x16x32 B-operand
// fragment for PV — zero-movement P, PV in MFMA32.
__global__ __launch_bounds__(256, 2) void attn_kernel(
        const unsigned short* __restrict__ qbuf, const unsigned short* __restrict__ kbuf,
        const unsigned short* __restrict__ vtbuf, const float* __restrict__ maskbuf,
        unsigned short* __restrict__ attnout) {
    __shared__ __attribute__((aligned(16))) unsigned short Ks[2][128 * 64];
    __shared__ __attribute__((aligned(16))) unsigned short Vs[2][64 * 128];

    int id = blockIdx.x;
    int combo = (id & 7) | (((id >> 7) & 3) << 3);   // same (b,h) stays on one XCD
    int qt = (id >> 3) & 15;
    int b = combo >> 4, h = combo & 15;
    int tid = threadIdx.x, lane = tid & 63, wave = tid >> 6;
    int lane15 = lane & 15, quad = lane >> 4;
    int q0 = qt * 128 + wave * 32;

    const unsigned short* Q  = qbuf  + (size_t)combo * 2048 * 64;
    const unsigned short* Kp = kbuf  + (size_t)combo * 2048 * 64;
    const unsigned short* Vt = vtbuf + (size_t)combo * 64 * 2048;
    const float* mb = maskbuf + b * 2048;

    // Q as 16x16x32 B-operand: B[n=lane15][k=quad*8+j]; two 16-q tiles, two k-halves
    short8 qf[2][2];
#pragma unroll
    for (int a = 0; a < 2; a++)
#pragma unroll
        for (int g = 0; g < 2; g++)
            qf[a][g] = *(const short8*)&Q[(size_t)(q0 + a * 16 + lane15) * 64 + g * 32 + quad * 8];

    // staging geometry (loop-invariant)
    int ci0 = tid;
    float m_run[2] = {-1e30f, -1e30f}, l_run[2] = {0.f, 0.f};
    f32x4 o[2][4];
#pragma unroll
    for (int a = 0; a < 2; a++)
#pragma unroll
        for (int c = 0; c < 4; c++) o[a][c] = (f32x4){0.f, 0.f, 0.f, 0.f};

    const f32x4 z4 = {0.f, 0.f, 0.f, 0.f};
    int x7 = lane15 & 7;

    // prologue: stage K/V tile 0 into buffer 0
#pragma unroll
    for (int r4 = 0; r4 < 4; r4++) {
        int ci = ci0 + r4 * 256;
        int kr = ci >> 3, kc = (ci & 7) ^ (kr & 7);
        GLL16(&Kp[(size_t)kr * 64 + kc * 8], &Ks[0][(size_t)ci * 8]);
        int vd = ci >> 4, vc = (ci & 15) ^ (vd & 15);
        GLL16(&Vt[(size_t)vd * 2048 + vc * 8], &Vs[0][(size_t)ci * 8]);
    }

    for (int it = 0; it < 16; it++) {
        int cur = it & 1;
        int kb = it * 128;
        __syncthreads();                       // tile[cur] ready; prior reads drained
        if (it < 15) {                         // prefetch tile[cur^1]
            int kn = kb + 128;
#pragma unroll
            for (int r4 = 0; r4 < 4; r4++) {
                int ci = ci0 + r4 * 256;
                int kr = ci >> 3, kc = (ci & 7) ^ (kr & 7);
                GLL16(&Kp[(size_t)(kn + kr) * 64 + kc * 8], &Ks[cur ^ 1][(size_t)ci * 8]);
                int vd = ci >> 4, vc = (ci & 15) ^ (vd & 15);
                GLL16(&Vt[(size_t)vd * 2048 + kn + vc * 8], &Vs[cur ^ 1][(size_t)ci * 8]);
            }
        }
        const unsigned short* ks = Ks[cur];
        const unsigned short* vs = Vs[cur];

        // ---- S^T = K.Q^T : 8 key-tiles x 2 q-tiles ----
        f32x4 s[2][8];
#pragma unroll
        for (int t = 0; t < 8; t++) {
            int row = t * 16 + lane15;
            short8 k0 = *(const short8*)&ks[row * 64 + (quad ^ x7) * 8];
            short8 k1 = *(const short8*)&ks[row * 64 + ((quad + 4) ^ x7) * 8];
            f32x4 t0 = MFMA32(k0, qf[0][0], z4);
            s[0][t] = MFMA32(k1, qf[0][1], t0);
            f32x4 t1 = MFMA32(k0, qf[1][0], z4);
            s[1][t] = MFMA32(k1, qf[1][1], t1);
        }
        // ---- mask (additive -1e30; scores already in log2 domain) ----
#pragma unroll
        for (int t = 0; t < 8; t++) {
            f32x4 mkt = *(const f32x4*)&mb[kb + t * 16 + quad * 4];
            s[0][t] += mkt;
            s[1][t] += mkt;
        }
        // ---- online softmax + pack P into MFMA32 B-frags ----
        short8 pb8[2][4];
#pragma unroll
        for (int a = 0; a < 2; a++) {
            f32x4 m4 = s[a][0];
#pragma unroll
            for (int t = 1; t < 8; t++) m4 = max4(m4, s[a][t]);
            float mx = fmaxf(fmaxf(m4[0], m4[1]), fmaxf(m4[2], m4[3]));
            mx = fmaxf(mx, __shfl_xor(mx, 16));
            mx = fmaxf(mx, __shfl_xor(mx, 32));
            float mnew = fmaxf(m_run[a], mx);
            float alpha = EXP2F(m_run[a] - mnew);
            m_run[a] = mnew;
            float ls = 0.f;
#pragma unroll
            for (int g = 0; g < 4; g++) {
                float e0 = EXP2F(s[a][2 * g][0] - mnew);
                float e1 = EXP2F(s[a][2 * g][1] - mnew);
                float e2 = EXP2F(s[a][2 * g][2] - mnew);
                float e3 = EXP2F(s[a][2 * g][3] - mnew);
                float f0 = EXP2F(s[a][2 * g + 1][0] - mnew);
                float f1 = EXP2F(s[a][2 * g + 1][1] - mnew);
                float f2 = EXP2F(s[a][2 * g + 1][2] - mnew);
                float f3 = EXP2F(s[a][2 * g + 1][3] - mnew);
                ls += ((e0 + e1) + (e2 + e3)) + ((f0 + f1) + (f2 + f3));
                union { uint4 u; short8 sv; } pu;   // bf16 truncation pack (P in [0,1])
                pu.u.x = __builtin_amdgcn_perm(__float_as_uint(e1), __float_as_uint(e0), 0x07060302u);
                pu.u.y = __builtin_amdgcn_perm(__float_as_uint(e3), __float_as_uint(e2), 0x07060302u);
                pu.u.z = __builtin_amdgcn_perm(__float_as_uint(f1), __float_as_uint(f0), 0x07060302u);
                pu.u.w = __builtin_amdgcn_perm(__float_as_uint(f3), __float_as_uint(f2), 0x07060302u);
                pb8[a][g] = pu.sv;
            }
            l_run[a] = l_run[a] * alpha + ls;
#pragma unroll
            for (int c = 0; c < 4; c++) o[a][c] *= alpha;
        }
        // ---- O^T += V^T.P^T : MFMA32, A-frag = one b128, shared by both q-tiles ----
#pragma unroll
        for (int c = 0; c < 4; c++) {
            int d = c * 16 + lane15;
#pragma unroll
            for (int g = 0; g < 4; g++) {
                int skc = (g * 4 + quad) ^ lane15;
                short8 vv = *(const short8*)&vs[d * 128 + skc * 8];
                o[0][c] = MFMA32(vv, pb8[0][g], o[0][c]);
                o[1][c] = MFMA32(vv, pb8[1][g], o[1][c]);
            }
        }
    }

    // ---- epilogue ----
#pragma unroll
    for (int a = 0; a < 2; a++) {
        float l = l_run[a];
        l += __shfl_xor(l, 16);
        l += __shfl_xor(l, 32);
        float rl = 1.0f / l;
        size_t row = (size_t)(b * 2048 + q0 + a * 16 + lane15) * 1024 + h * 64 + quad * 4;
#pragma unroll
        for (int c = 0; c < 4; c++) {
            ushort4 pk;
            pk.x = f2b(o[a][c][0] * rl);
            pk.y = f2b(o[a][c][1] * rl);
            pk.z = f2b(o[a][c][2] * rl);
            pk.w = f2b(o[a][c][3] * rl);
            *(ushort4*)&attnout[row + c * 16] = pk;
        }
    }
}

extern "C" void kernel_launch(void* const* d_in, const int* in_sizes, int n_in,
                              void* d_out, int out_size, void* d_ws, size_t ws_size,
                              hipStream_t stream) {
    const float* x    = (const float*)d_in[0];
    const float* wq_w = (const float*)d_in[1];
    const float* wq_b = (const float*)d_in[2];
    const float* wk_w = (const float*)d_in[3];
    const float* wk_b = (const float*)d_in[4];
    const float* wv_w = (const float*)d_in[5];
    const float* wv_b = (const float*)d_in[6];
    const float* wo_w = (const float*)d_in[7];
    const float* wo_b = (const float*)d_in[8];
    float* out = (float*)d_out;

    char* ws = (char*)d_ws;
    size_t off = 0;
    unsigned short* xb      = (unsigned short*)(ws + off); off += (size_t)4096 * 1024 * 2;
    unsigned short* wb      = (unsigned short*)(ws + off); off += (size_t)4 * 1024 * 1024 * 2;
    unsigned short* qbuf    = (unsigned short*)(ws + off); off += (size_t)4096 * 1024 * 2;
    unsigned short* kbuf    = (unsigned short*)(ws + off); off += (size_t)4096 * 1024 * 2;
    unsigned short* vbuf    = (unsigned short*)(ws + off); off += (size_t)4096 * 1024 * 2;
    unsigned short* attnout = (unsigned short*)(ws + off); off += (size_t)4096 * 1024 * 2;
    float* maskbuf          = (float*)(ws + off);          off += 4096 * 4;

    unsigned short* wqb = wb;
    unsigned short* wkb = wb + (1u << 20);
    unsigned short* wvb = wb + (2u << 20);
    unsigned short* wob = wb + (3u << 20);

    cvt_all<<<8192, 256, 0, stream>>>(x, wq_w, wk_w, wv_w, wo_w, xb, wb, maskbuf);

    gemm_qkv<<<dim3(24, 32), 256, 0, stream>>>(xb, wqb, wkb, wvb,
                                               wq_b, wk_b, wv_b, qbuf, kbuf, vbuf);

    attn_kernel<<<512, 256, 0, stream>>>(qbuf, kbuf, vbuf, maskbuf, attnout);

    gemm_proj<<<dim3(8, 64), 256, 0, stream>>>(attnout, wob, wo_b, out);
}